// Round 7
// baseline (326.084 us; speedup 1.0000x reference)
//
#include <hip/hip_runtime.h>
#include <hip/hip_bf16.h>
#include <cstdint>
#include <cstddef>

#define NB 2
#define NS 2048
#define ND 1024
#define NH 16
#define NDK 64
#define NT (NS / 64)

typedef __attribute__((ext_vector_type(4))) float f32x4;
typedef __attribute__((ext_vector_type(8))) short bf16x8;

#define MFMA_16x16x32_BF16(a,b,c) __builtin_amdgcn_mfma_f32_16x16x32_bf16((a),(b),(c),0,0,0)

__device__ __forceinline__ uint16_t f2bf(float f){
  uint32_t u = __float_as_uint(f);
  u += 0x7fffu + ((u >> 16) & 1u);   // round-to-nearest-even
  return (uint16_t)(u >> 16);
}
__device__ __forceinline__ uint32_t bfpack2(float a, float b){
  uint32_t r;
  asm volatile("v_cvt_pk_bf16_f32 %0, %1, %2" : "=v"(r) : "v"(a), "v"(b));
  return r;
}
__device__ __forceinline__ void gload_lds16(const void* g, void* l){
  __builtin_amdgcn_global_load_lds((const __attribute__((address_space(1))) void*)g,
                                   (__attribute__((address_space(3))) void*)l, 16, 0, 0);
}

// ---------------- f32 -> bf16 converts (fused launches) ---------------------
__global__ void cvt3_f32_bf16(const float* __restrict__ a, const float* __restrict__ b2,
                              const float* __restrict__ c, uint16_t* __restrict__ oa,
                              uint16_t* __restrict__ ob, uint16_t* __restrict__ oc, int n8){
  const float* in = (blockIdx.y == 0) ? a : (blockIdx.y == 1) ? b2 : c;
  uint16_t* out   = (blockIdx.y == 0) ? oa : (blockIdx.y == 1) ? ob : oc;
  int i0 = blockIdx.x * blockDim.x + threadIdx.x;
  int stride = gridDim.x * blockDim.x;
  for(int i = i0; i < n8; i += stride){
    const float4* p = (const float4*)(in) + (size_t)i * 2;
    float4 x = p[0], y = p[1];
    bf16x8 o;
    o[0]=(short)f2bf(x.x); o[1]=(short)f2bf(x.y); o[2]=(short)f2bf(x.z); o[3]=(short)f2bf(x.w);
    o[4]=(short)f2bf(y.x); o[5]=(short)f2bf(y.y); o[6]=(short)f2bf(y.z); o[7]=(short)f2bf(y.w);
    *((bf16x8*)(out) + i) = o;
  }
}
__global__ void cvt4_f32_bf16(const float* __restrict__ a, const float* __restrict__ b2,
                              const float* __restrict__ c, const float* __restrict__ d,
                              uint16_t* __restrict__ oa, uint16_t* __restrict__ ob,
                              uint16_t* __restrict__ oc, uint16_t* __restrict__ od, int n8){
  const float* in = (blockIdx.y == 0) ? a : (blockIdx.y == 1) ? b2 : (blockIdx.y == 2) ? c : d;
  uint16_t* out   = (blockIdx.y == 0) ? oa : (blockIdx.y == 1) ? ob : (blockIdx.y == 2) ? oc : od;
  int i0 = blockIdx.x * blockDim.x + threadIdx.x;
  int stride = gridDim.x * blockDim.x;
  for(int i = i0; i < n8; i += stride){
    const float4* p = (const float4*)(in) + (size_t)i * 2;
    float4 x = p[0], y = p[1];
    bf16x8 o;
    o[0]=(short)f2bf(x.x); o[1]=(short)f2bf(x.y); o[2]=(short)f2bf(x.z); o[3]=(short)f2bf(x.w);
    o[4]=(short)f2bf(y.x); o[5]=(short)f2bf(y.y); o[6]=(short)f2bf(y.z); o[7]=(short)f2bf(y.w);
    *((bf16x8*)(out) + i) = o;
  }
}

// ---------------- int32 mask -> packed bits (1 = keep) ----------------------
__global__ void mask_bits(const int* __restrict__ mask, unsigned long long* __restrict__ bits, int nchunks){
  int wid  = (blockIdx.x * blockDim.x + threadIdx.x) >> 6;
  int lane = threadIdx.x & 63;
  int nw   = (gridDim.x * blockDim.x) >> 6;
  for(int c = wid; c < nchunks; c += nw){
    int mv = mask[(size_t)c * 64 + lane];
    unsigned long long bb = __ballot(mv != 0);
    if(lane == 0) bits[c] = bb;
  }
}

// ---------------- GEMM: C[m,n] = sum_k A[m,k]*W[n,k] + bias[n] --------------
// 128x128 tile, BK=64, gload_lds(16B) staging, XOR-swizzled LDS, hoisted addrs.
// vtz: if z == vtz, write output transposed per-head: Vt[(b,h),dk,s] (bf16).
template<bool OUTF32>
__global__ __launch_bounds__(256, 4)
void gemm_bt(const uint16_t* __restrict__ A0, const uint16_t* __restrict__ A1, const uint16_t* __restrict__ A2,
             const uint16_t* __restrict__ W0, const uint16_t* __restrict__ W1, const uint16_t* __restrict__ W2,
             const float* __restrict__ b0, const float* __restrict__ b1, const float* __restrict__ b2,
             void* __restrict__ C0, void* __restrict__ C1, void* __restrict__ C2,
             int M, int N, int K, int vtz)
{
  const int z = blockIdx.z;
  const uint16_t* A   = (z == 0) ? A0 : (z == 1) ? A1 : A2;
  const uint16_t* W   = (z == 0) ? W0 : (z == 1) ? W1 : W2;
  const float*   bias = (z == 0) ? b0 : (z == 1) ? b1 : b2;
  void*          Cout = (z == 0) ? C0 : (z == 1) ? C1 : C2;

  __shared__ __align__(16) uint16_t Asm[128 * 64];
  __shared__ __align__(16) uint16_t Bsm[128 * 64];

  const int t = threadIdx.x;
  const int lane = t & 63, w = t >> 6;
  const int l15 = lane & 15, g = lane >> 4;
  const int bm = blockIdx.y * 128, bn = blockIdx.x * 128;
  const int wr = (w >> 1) * 64, wc = (w & 1) * 64;

  f32x4 acc[4][4] = {};

  const int srow = lane >> 3;
  const int schk = (lane & 7) ^ srow;

  const uint16_t* gA = A + (size_t)(bm + w * 32 + srow) * K + schk * 8;
  const uint16_t* gB = W + (size_t)(bn + w * 32 + srow) * K + schk * 8;
  uint16_t* lA = &Asm[(w * 32) * 64];
  uint16_t* lB = &Bsm[(w * 32) * 64];

  // hoisted frag read offsets (loop-invariant)
  const int xr = l15 & 7;
  int aOff[2][4], bOff[2][4];
  #pragma unroll
  for(int kk = 0; kk < 2; ++kk)
    #pragma unroll
    for(int m = 0; m < 4; ++m){
      aOff[kk][m] = (wr + m*16 + l15) * 64 + (((kk*4 + g) ^ xr) << 3);
      bOff[kk][m] = (wc + m*16 + l15) * 64 + (((kk*4 + g) ^ xr) << 3);
    }

  for(int k0 = 0; k0 < K; k0 += 64){
    #pragma unroll
    for(int j = 0; j < 4; ++j){
      gload_lds16(gA + (size_t)(8 * j) * K, lA + (8 * j) * 64);
      gload_lds16(gB + (size_t)(8 * j) * K, lB + (8 * j) * 64);
    }
    gA += 64; gB += 64;
    __syncthreads();
    #pragma unroll
    for(int kk = 0; kk < 2; ++kk){
      bf16x8 af[4], bfr[4];
      #pragma unroll
      for(int m = 0; m < 4; ++m) af[m]  = *(const bf16x8*)&Asm[aOff[kk][m]];
      #pragma unroll
      for(int n = 0; n < 4; ++n) bfr[n] = *(const bf16x8*)&Bsm[bOff[kk][n]];
      #pragma unroll
      for(int m = 0; m < 4; ++m)
        #pragma unroll
        for(int n = 0; n < 4; ++n)
          acc[m][n] = MFMA_16x16x32_BF16(af[m], bfr[n], acc[m][n]);
    }
    __syncthreads();
  }

  if(z == vtz){
    // transposed per-head epilogue: Vt[((b*NH+h)*NDK+dk)*NS + s], s = row..row+3
    uint16_t* Vt = (uint16_t*)Cout;
    #pragma unroll
    for(int m = 0; m < 4; ++m){
      const int row = bm + wr + m*16 + g*4;
      const int bb = row >> 11, ss = row & (NS - 1);
      #pragma unroll
      for(int n = 0; n < 4; ++n){
        const int col = bn + wc + n*16 + l15;
        const float bv = bias[col];
        float v0 = acc[m][n][0] + bv, v1 = acc[m][n][1] + bv;
        float v2 = acc[m][n][2] + bv, v3 = acc[m][n][3] + bv;
        uint2 pk; pk.x = bfpack2(v0, v1); pk.y = bfpack2(v2, v3);
        size_t dst = ((size_t)(bb * NH + (col >> 6)) * NDK + (col & 63)) * NS + ss;
        *(uint2*)&Vt[dst] = pk;
      }
    }
  } else {
    #pragma unroll
    for(int m = 0; m < 4; ++m){
      const int row = bm + wr + m*16 + g*4;
      #pragma unroll
      for(int n = 0; n < 4; ++n){
        const int col = bn + wc + n*16 + l15;
        const float bv = bias[col];
        #pragma unroll
        for(int j = 0; j < 4; ++j){
          float v = acc[m][n][j] + bv;
          if (OUTF32) ((float*)Cout)[(size_t)(row + j) * N + col] = v;
          else        ((uint16_t*)Cout)[(size_t)(row + j) * N + col] = f2bf(v);
        }
      }
    }
  }
}

// ---------------- Flash attention (barrier-free, direct-global K/V) ---------
// K/V per (b,h) is 512KB -> L2-resident; lanes read MFMA fragments straight
// from global (same addresses the swizzled-LDS path reconstructed). No LDS
// staging, no DMA drain, no __syncthreads in the loop: waves fully
// independent; latency hidden by 16 waves/CU TLP + compiler vmcnt interleave.
__global__ __launch_bounds__(256, 4)
void attn_fwd(const uint16_t* __restrict__ Qp, const uint16_t* __restrict__ Kp,
              const uint16_t* __restrict__ Vtg, const uint2* __restrict__ Mbits,
              uint16_t* __restrict__ Xo)
{
  __shared__ __align__(16) uint16_t Psm[4][16 * 64];

  const int t = threadIdx.x, lane = t & 63, w = t >> 6;
  const int l15 = lane & 15, g = lane >> 4;
  const int b = blockIdx.z, h = blockIdx.y, q0 = blockIdx.x * 64;
  const int qbase = q0 + w * 16;

  bf16x8 qf0, qf1;
  {
    const uint16_t* qptr = Qp + (size_t)(b * NS + qbase + l15) * ND + h * NDK + g * 8;
    qf0 = *(const bf16x8*)(qptr);
    qf1 = *(const bf16x8*)(qptr + 32);
  }

  bf16x8 ones;
  #pragma unroll
  for(int e = 0; e < 8; ++e) ones[e] = (short)0x3F80;   // bf16 1.0

  f32x4 acc[4] = {};
  f32x4 acl = {};
  const float SCL = 0.125f * 1.44269504f;    // log2(e)/sqrt(DK)
  const float MC  = 23.0831f;                // 16 (scaled sigma) * log2(e)

  // per-lane global fragment pointers (exactly the data the LDS path held)
  const uint16_t* pK0 = Kp  + (size_t)(b * NS + l15) * ND + h * NDK + g * 8;
  const uint16_t* pV0 = Vtg + ((size_t)(b * NH + h) * NDK + l15) * NS + g * 8;
  const uint2* Mptr = Mbits + (size_t)(b * NS + qbase + l15) * (NS / 64);

  // hoisted P-LDS offsets
  const int xorw = (l15 & 7) << 3;
  const int prow = l15 * 64;
  int pW[4], pR[2];
  #pragma unroll
  for(int i = 0; i < 4; ++i) pW[i] = prow + ((16 * i + g * 4) ^ xorw);
  #pragma unroll
  for(int c2 = 0; c2 < 2; ++c2) pR[c2] = prow + ((c2 * 32 + g * 8) ^ xorw);
  uint16_t* PsmW = Psm[w];

  for(int ti = 0; ti < NT; ++ti){
    // fragment loads for this tile (issued up front; QK^T waits only on K)
    bf16x8 kf[8], vf[8];
    #pragma unroll
    for(int i = 0; i < 4; ++i){
      const uint16_t* p = pK0 + (size_t)(i * 16) * ND;
      kf[2*i]   = *(const bf16x8*)(p);          // k-slice 0..31  (chunk g)
      kf[2*i+1] = *(const bf16x8*)(p + 32);     // k-slice 32..63 (chunk g+4)
    }
    #pragma unroll
    for(int tt = 0; tt < 4; ++tt){
      const uint16_t* p = pV0 + (size_t)(tt * 16) * NS;
      vf[tt]     = *(const bf16x8*)(p);         // kv chunk c2=0
      vf[4 + tt] = *(const bf16x8*)(p + 32);    // kv chunk c2=1
    }
    const uint2 mm = Mptr[ti];
    pK0 += 64 * ND; pV0 += 64;

    // QK^T swapped: s4[i] row=kv(16i+g*4+j), col=q(l15); RAW scores
    f32x4 s4[4];
    __builtin_amdgcn_s_setprio(1);
    #pragma unroll
    for(int i = 0; i < 4; ++i){
      f32x4 zr = {};
      zr = MFMA_16x16x32_BF16(kf[2*i],   qf0, zr);
      zr = MFMA_16x16x32_BF16(kf[2*i+1], qf1, zr);
      s4[i] = zr;
    }
    __builtin_amdgcn_s_setprio(0);

    // p = exp2(s*SCL - MC), masked by sign-extended bitfield
    const uint32_t w0 = mm.x >> (g * 4);
    const uint32_t w1 = mm.y >> (g * 4);
    #pragma unroll
    for(int i = 0; i < 4; ++i){
      const uint32_t ww = (i < 2) ? w0 : w1;
      #pragma unroll
      for(int j = 0; j < 4; ++j){
        const int bitpos = (i & 1) * 16 + j;
        float e = exp2f(fmaf(s4[i][j], SCL, -MC));
        uint32_t sm = (uint32_t)(((int)(ww << (31 - bitpos))) >> 31);
        s4[i][j] = __uint_as_float(sm & __float_as_uint(e));
      }
    }

    // pack P -> per-wave LDS (b64 writes)
    #pragma unroll
    for(int i = 0; i < 4; ++i){
      uint2 pk;
      pk.x = bfpack2(s4[i][0], s4[i][1]);
      pk.y = bfpack2(s4[i][2], s4[i][3]);
      *(uint2*)&PsmW[pW[i]] = pk;
    }

    // PV (+ denominator via ones-column MFMA)
    __builtin_amdgcn_s_setprio(1);
    #pragma unroll
    for(int c2 = 0; c2 < 2; ++c2){
      bf16x8 pf = *(const bf16x8*)&PsmW[pR[c2]];
      acl = MFMA_16x16x32_BF16(pf, ones, acl);
      #pragma unroll
      for(int tt = 0; tt < 4; ++tt)
        acc[tt] = MFMA_16x16x32_BF16(pf, vf[c2 * 4 + tt], acc[tt]);
    }
    __builtin_amdgcn_s_setprio(0);
  }

  // finalize: l already in output-row layout (row = g*4+j)
  #pragma unroll
  for(int j = 0; j < 4; ++j){
    const float inv = 1.0f / acl[j];
    const int qr = qbase + g * 4 + j;
    #pragma unroll
    for(int tt = 0; tt < 4; ++tt)
      Xo[(size_t)(b * NS + qr) * ND + h * NDK + tt * 16 + l15] = f2bf(acc[tt][j] * inv);
  }
}

// ---------------- host launch ------------------------------------------------
extern "C" void kernel_launch(void* const* d_in, const int* in_sizes, int n_in,
                              void* d_out, int out_size, void* d_ws, size_t ws_size,
                              hipStream_t stream)
{
  const float* query = (const float*)d_in[0];
  const float* key   = (const float*)d_in[1];
  const float* value = (const float*)d_in[2];
  const int*   mask  = (const int*)d_in[3];
  const float* Wq = (const float*)d_in[4];
  const float* bq = (const float*)d_in[5];
  const float* Wk = (const float*)d_in[6];
  const float* bk = (const float*)d_in[7];
  const float* Wv = (const float*)d_in[8];
  const float* bv = (const float*)d_in[9];
  const float* Wo = (const float*)d_in[10];
  const float* bo = (const float*)d_in[11];
  float* out = (float*)d_out;

  const size_t NX = (size_t)NB * NS * ND;   // 4,194,304
  const size_t NW = (size_t)ND * ND;        // 1,048,576

  uint16_t* ws  = (uint16_t*)d_ws;
  uint16_t* Xq  = ws;            // bf16 activations; dead after proj -> Mbits here
  uint16_t* Xk  = Xq  + NX;
  uint16_t* Xv  = Xk  + NX;
  uint16_t* Wqb = Xv  + NX;
  uint16_t* Wkb = Wqb + NW;
  uint16_t* Wvb = Wkb + NW;
  uint16_t* Wob = Wvb + NW;
  uint16_t* Qp  = Wob + NW;
  uint16_t* Kp  = Qp  + NX;
  uint16_t* Vt  = Kp  + NX;      // V^T written directly by proj epilogue (z==2)
  uint16_t* Xa  = Vt  + NX;

  unsigned long long* Mb = (unsigned long long*)Xq;   // 131072 u64 = 1MB

  cvt3_f32_bf16<<<dim3(2048, 3), 256, 0, stream>>>(query, key, value, Xq, Xk, Xv, (int)(NX / 8));
  cvt4_f32_bf16<<<dim3(512, 4), 256, 0, stream>>>(Wq, Wk, Wv, Wo, Wqb, Wkb, Wvb, Wob, (int)(NW / 8));

  dim3 gproj(ND / 128, (NB * NS) / 128, 3);
  gemm_bt<false><<<gproj, 256, 0, stream>>>(Xq, Xk, Xv,
                                            Wqb, Wkb, Wvb,
                                            bq, bk, bv,
                                            (void*)Qp, (void*)Kp, (void*)Vt,
                                            NB * NS, ND, ND, 2);

  // activations dead -> build mask bits in their place
  {
    int nchunks = (int)((size_t)NB * NS * NS / 64);   // 131072
    mask_bits<<<2048, 256, 0, stream>>>(mask, Mb, nchunks);
  }

  attn_fwd<<<dim3(NS / 64, NH, NB), 256, 0, stream>>>(Qp, Kp, Vt, (const uint2*)Mb, Xa);

  dim3 gout(ND / 128, (NB * NS) / 128, 1);
  gemm_bt<true><<<gout, 256, 0, stream>>>(Xa, Xa, Xa,
                                          Wob, Wob, Wob,
                                          bo, bo, bo,
                                          (void*)out, (void*)out, (void*)out,
                                          NB * NS, ND, ND, -1);
}

// Round 8
// 160.755 us; speedup vs baseline: 2.0285x; 2.0285x over previous
//
#include <hip/hip_runtime.h>
#include <hip/hip_bf16.h>
#include <cstdint>
#include <cstddef>

#define NB 2
#define NS 2048
#define ND 1024
#define NH 16
#define NDK 64
#define NT (NS / 64)

typedef __attribute__((ext_vector_type(4))) float f32x4;
typedef __attribute__((ext_vector_type(8))) short bf16x8;

#define MFMA_16x16x32_BF16(a,b,c) __builtin_amdgcn_mfma_f32_16x16x32_bf16((a),(b),(c),0,0,0)

__device__ __forceinline__ uint16_t f2bf(float f){
  uint32_t u = __float_as_uint(f);
  u += 0x7fffu + ((u >> 16) & 1u);   // round-to-nearest-even
  return (uint16_t)(u >> 16);
}
__device__ __forceinline__ uint32_t bfpack2(float a, float b){
  uint32_t r;
  asm volatile("v_cvt_pk_bf16_f32 %0, %1, %2" : "=v"(r) : "v"(a), "v"(b));
  return r;
}
__device__ __forceinline__ void gload_lds16(const void* g, void* l){
  __builtin_amdgcn_global_load_lds((const __attribute__((address_space(1))) void*)g,
                                   (__attribute__((address_space(3))) void*)l, 16, 0, 0);
}

// ------- fused prep: y=0..2 cvt activations f32->bf16, y=3 mask->bits -------
__global__ void prep_inputs(const float* __restrict__ a, const float* __restrict__ b2,
                            const float* __restrict__ c, uint16_t* __restrict__ oa,
                            uint16_t* __restrict__ ob, uint16_t* __restrict__ oc,
                            const int* __restrict__ mask, unsigned long long* __restrict__ bits,
                            int n8, int nchunks){
  if(blockIdx.y == 3){
    int wid  = (blockIdx.x * blockDim.x + threadIdx.x) >> 6;
    int lane = threadIdx.x & 63;
    int nw   = (gridDim.x * blockDim.x) >> 6;
    for(int ch = wid; ch < nchunks; ch += nw){
      int mv = mask[(size_t)ch * 64 + lane];
      unsigned long long bb = __ballot(mv != 0);
      if(lane == 0) bits[ch] = bb;
    }
    return;
  }
  const float* in = (blockIdx.y == 0) ? a : (blockIdx.y == 1) ? b2 : c;
  uint16_t* out   = (blockIdx.y == 0) ? oa : (blockIdx.y == 1) ? ob : oc;
  int i0 = blockIdx.x * blockDim.x + threadIdx.x;
  int stride = gridDim.x * blockDim.x;
  for(int i = i0; i < n8; i += stride){
    const float4* p = (const float4*)(in) + (size_t)i * 2;
    float4 x = p[0], y = p[1];
    bf16x8 o;
    o[0]=(short)f2bf(x.x); o[1]=(short)f2bf(x.y); o[2]=(short)f2bf(x.z); o[3]=(short)f2bf(x.w);
    o[4]=(short)f2bf(y.x); o[5]=(short)f2bf(y.y); o[6]=(short)f2bf(y.z); o[7]=(short)f2bf(y.w);
    *((bf16x8*)(out) + i) = o;
  }
}
__global__ void cvt4_f32_bf16(const float* __restrict__ a, const float* __restrict__ b2,
                              const float* __restrict__ c, const float* __restrict__ d,
                              uint16_t* __restrict__ oa, uint16_t* __restrict__ ob,
                              uint16_t* __restrict__ oc, uint16_t* __restrict__ od, int n8){
  const float* in = (blockIdx.y == 0) ? a : (blockIdx.y == 1) ? b2 : (blockIdx.y == 2) ? c : d;
  uint16_t* out   = (blockIdx.y == 0) ? oa : (blockIdx.y == 1) ? ob : (blockIdx.y == 2) ? oc : od;
  int i0 = blockIdx.x * blockDim.x + threadIdx.x;
  int stride = gridDim.x * blockDim.x;
  for(int i = i0; i < n8; i += stride){
    const float4* p = (const float4*)(in) + (size_t)i * 2;
    float4 x = p[0], y = p[1];
    bf16x8 o;
    o[0]=(short)f2bf(x.x); o[1]=(short)f2bf(x.y); o[2]=(short)f2bf(x.z); o[3]=(short)f2bf(x.w);
    o[4]=(short)f2bf(y.x); o[5]=(short)f2bf(y.y); o[6]=(short)f2bf(y.z); o[7]=(short)f2bf(y.w);
    *((bf16x8*)(out) + i) = o;
  }
}

// ---------------- GEMM: C[m,n] = sum_k A[m,k]*W[n,k] + bias[n] --------------
// 128x128 tile, BK=64, gload_lds(16B) staging, XOR-swizzled LDS, hoisted addrs.
// vtz: if z == vtz, write output transposed per-head: Vt[(b,h),dk,s] (bf16).
template<bool OUTF32>
__global__ __launch_bounds__(256, 4)
void gemm_bt(const uint16_t* __restrict__ A0, const uint16_t* __restrict__ A1, const uint16_t* __restrict__ A2,
             const uint16_t* __restrict__ W0, const uint16_t* __restrict__ W1, const uint16_t* __restrict__ W2,
             const float* __restrict__ b0, const float* __restrict__ b1, const float* __restrict__ b2,
             void* __restrict__ C0, void* __restrict__ C1, void* __restrict__ C2,
             int M, int N, int K, int vtz)
{
  const int z = blockIdx.z;
  const uint16_t* A   = (z == 0) ? A0 : (z == 1) ? A1 : A2;
  const uint16_t* W   = (z == 0) ? W0 : (z == 1) ? W1 : W2;
  const float*   bias = (z == 0) ? b0 : (z == 1) ? b1 : b2;
  void*          Cout = (z == 0) ? C0 : (z == 1) ? C1 : C2;

  __shared__ __align__(16) uint16_t Asm[128 * 64];
  __shared__ __align__(16) uint16_t Bsm[128 * 64];

  const int t = threadIdx.x;
  const int lane = t & 63, w = t >> 6;
  const int l15 = lane & 15, g = lane >> 4;
  const int bm = blockIdx.y * 128, bn = blockIdx.x * 128;
  const int wr = (w >> 1) * 64, wc = (w & 1) * 64;

  f32x4 acc[4][4] = {};

  const int srow = lane >> 3;
  const int schk = (lane & 7) ^ srow;

  const uint16_t* gA = A + (size_t)(bm + w * 32 + srow) * K + schk * 8;
  const uint16_t* gB = W + (size_t)(bn + w * 32 + srow) * K + schk * 8;
  uint16_t* lA = &Asm[(w * 32) * 64];
  uint16_t* lB = &Bsm[(w * 32) * 64];

  // hoisted frag read offsets (loop-invariant)
  const int xr = l15 & 7;
  int aOff[2][4], bOff[2][4];
  #pragma unroll
  for(int kk = 0; kk < 2; ++kk)
    #pragma unroll
    for(int m = 0; m < 4; ++m){
      aOff[kk][m] = (wr + m*16 + l15) * 64 + (((kk*4 + g) ^ xr) << 3);
      bOff[kk][m] = (wc + m*16 + l15) * 64 + (((kk*4 + g) ^ xr) << 3);
    }

  for(int k0 = 0; k0 < K; k0 += 64){
    #pragma unroll
    for(int j = 0; j < 4; ++j){
      gload_lds16(gA + (size_t)(8 * j) * K, lA + (8 * j) * 64);
      gload_lds16(gB + (size_t)(8 * j) * K, lB + (8 * j) * 64);
    }
    gA += 64; gB += 64;
    __syncthreads();
    #pragma unroll
    for(int kk = 0; kk < 2; ++kk){
      bf16x8 af[4], bfr[4];
      #pragma unroll
      for(int m = 0; m < 4; ++m) af[m]  = *(const bf16x8*)&Asm[aOff[kk][m]];
      #pragma unroll
      for(int n = 0; n < 4; ++n) bfr[n] = *(const bf16x8*)&Bsm[bOff[kk][n]];
      #pragma unroll
      for(int m = 0; m < 4; ++m)
        #pragma unroll
        for(int n = 0; n < 4; ++n)
          acc[m][n] = MFMA_16x16x32_BF16(af[m], bfr[n], acc[m][n]);
    }
    __syncthreads();
  }

  if(z == vtz){
    // transposed per-head epilogue: Vt[((b*NH+h)*NDK+dk)*NS + s], s = row..row+3
    uint16_t* Vt = (uint16_t*)Cout;
    #pragma unroll
    for(int m = 0; m < 4; ++m){
      const int row = bm + wr + m*16 + g*4;
      const int bb = row >> 11, ss = row & (NS - 1);
      #pragma unroll
      for(int n = 0; n < 4; ++n){
        const int col = bn + wc + n*16 + l15;
        const float bv = bias[col];
        float v0 = acc[m][n][0] + bv, v1 = acc[m][n][1] + bv;
        float v2 = acc[m][n][2] + bv, v3 = acc[m][n][3] + bv;
        uint2 pk; pk.x = bfpack2(v0, v1); pk.y = bfpack2(v2, v3);
        size_t dst = ((size_t)(bb * NH + (col >> 6)) * NDK + (col & 63)) * NS + ss;
        *(uint2*)&Vt[dst] = pk;
      }
    }
  } else {
    #pragma unroll
    for(int m = 0; m < 4; ++m){
      const int row = bm + wr + m*16 + g*4;
      #pragma unroll
      for(int n = 0; n < 4; ++n){
        const int col = bn + wc + n*16 + l15;
        const float bv = bias[col];
        #pragma unroll
        for(int j = 0; j < 4; ++j){
          float v = acc[m][n][j] + bv;
          if (OUTF32) ((float*)Cout)[(size_t)(row + j) * N + col] = v;
          else        ((uint16_t*)Cout)[(size_t)(row + j) * N + col] = f2bf(v);
        }
      }
    }
  }
}

// ---------------- Flash attention -------------------------------------------
// R6 dbuf-LDS structure + T4 counted-vmcnt 2-barrier schedule:
//   issue G(t+1)+mask(t+1) [5 vmem] -> vmcnt(5) -> barrier -> compute(t)
//   -> lgkmcnt(0) -> barrier
// The 5 newest loads stay in flight ACROSS the barriers (never drained to 0
// in the main loop); tile-t loads get a full iteration of latency slack.
__device__ __forceinline__ int swz64(int r, int chunk){
  return r * 64 + (((chunk) ^ (r & 7)) << 3);
}

__global__ __launch_bounds__(256, 4)
void attn_fwd(const uint16_t* __restrict__ Qp, const uint16_t* __restrict__ Kp,
              const uint16_t* __restrict__ Vtg, const uint2* __restrict__ Mbits,
              uint16_t* __restrict__ Xo)
{
  __shared__ __align__(16) uint16_t Ksm[2][64 * 64];
  __shared__ __align__(16) uint16_t Vtsm[2][64 * 64];
  __shared__ __align__(16) uint16_t Psm[4][16 * 64];

  const int t = threadIdx.x, lane = t & 63, w = t >> 6;
  const int l15 = lane & 15, g = lane >> 4;
  const int b = blockIdx.z, h = blockIdx.y, q0 = blockIdx.x * 64;
  const int qbase = q0 + w * 16;

  bf16x8 qf0, qf1;
  {
    const uint16_t* qptr = Qp + (size_t)(b * NS + qbase + l15) * ND + h * NDK + g * 8;
    qf0 = *(const bf16x8*)(qptr);
    qf1 = *(const bf16x8*)(qptr + 32);
  }

  bf16x8 ones;
  #pragma unroll
  for(int e = 0; e < 8; ++e) ones[e] = (short)0x3F80;   // bf16 1.0

  f32x4 acc[4] = {};
  f32x4 acl = {};
  const float SCL = 0.125f * 1.44269504f;    // log2(e)/sqrt(DK)
  const float MC  = 23.0831f;                // 16 (scaled sigma) * log2(e)

  const int srow = lane >> 3;
  const int schk = (lane & 7) ^ srow;

  // global staging pointers, bumped per tile
  const uint16_t* gK0 = Kp + (size_t)(b * NS + w * 16 + srow) * ND + h * NDK + schk * 8;
  const uint16_t* gK1 = gK0 + 8 * ND;
  const uint16_t* gV0 = Vtg + (size_t)(b * NH + h) * NDK * NS + (size_t)(w * 16 + srow) * NS + schk * 8;
  const uint16_t* gV1 = gV0 + 8 * NS;

  // LDS staging dest bases (wave-uniform); buffer select via +cur*4096
  uint16_t* lK = &Ksm[0][(w * 16) * 64];
  uint16_t* lV = &Vtsm[0][(w * 16) * 64];

  // hoisted LDS read offsets (loop-invariant)
  int kOffA[4], kOffB[4], vOff[2][4];
  #pragma unroll
  for(int i = 0; i < 4; ++i){
    kOffA[i] = swz64(i * 16 + l15, g);
    kOffB[i] = swz64(i * 16 + l15, g + 4);
  }
  #pragma unroll
  for(int c2 = 0; c2 < 2; ++c2)
    #pragma unroll
    for(int tt = 0; tt < 4; ++tt)
      vOff[c2][tt] = swz64(tt * 16 + l15, c2 * 4 + g);
  const int xorw = (l15 & 7) << 3;
  const int prow = l15 * 64;
  int pW[4], pR[2];
  #pragma unroll
  for(int i = 0; i < 4; ++i) pW[i] = prow + ((16 * i + g * 4) ^ xorw);
  #pragma unroll
  for(int c2 = 0; c2 < 2; ++c2) pR[c2] = prow + ((c2 * 32 + g * 8) ^ xorw);
  uint16_t* PsmW = Psm[w];

  const uint2* Mptr = Mbits + (size_t)(b * NS + qbase + l15) * (NS / 64);

  // prologue: stage tile 0 into buffer 0 (4 gloads + 1 mask load = 5 vmem)
  gload_lds16(gK0, lK);
  gload_lds16(gK1, lK + 8 * 64);
  gload_lds16(gV0, lV);
  gload_lds16(gV1, lV + 8 * 64);
  uint2 mmc = Mptr[0];
  gK0 += 64 * ND; gK1 += 64 * ND; gV0 += 64; gV1 += 64;

  int cur = 0;
  for(int ti = 0; ti < NT; ++ti){
    // issue next-tile staging (5 vmem ops), then counted wait for THIS tile
    uint2 mmn;
    if(ti + 1 < NT){
      const int nc = (cur ^ 1) * 4096;
      gload_lds16(gK0, lK + nc);
      gload_lds16(gK1, lK + nc + 8 * 64);
      gload_lds16(gV0, lV + nc);
      gload_lds16(gV1, lV + nc + 8 * 64);
      mmn = Mptr[ti + 1];
      gK0 += 64 * ND; gK1 += 64 * ND; gV0 += 64; gV1 += 64;
      asm volatile("s_waitcnt vmcnt(5)" ::: "memory");
    } else {
      asm volatile("s_waitcnt vmcnt(0)" ::: "memory");
    }
    __builtin_amdgcn_s_barrier();   // everyone's tile-ti DMA landed

    const uint16_t* Kc = &Ksm[0][cur * 4096];
    const uint16_t* Vc = &Vtsm[0][cur * 4096];

    // QK^T swapped: s4[i] row=kv(16i+g*4+j), col=q(l15); RAW scores
    f32x4 s4[4];
    __builtin_amdgcn_s_setprio(1);
    #pragma unroll
    for(int i = 0; i < 4; ++i){
      bf16x8 kf0 = *(const bf16x8*)&Kc[kOffA[i]];
      bf16x8 kf1 = *(const bf16x8*)&Kc[kOffB[i]];
      f32x4 zr = {};
      zr = MFMA_16x16x32_BF16(kf0, qf0, zr);
      zr = MFMA_16x16x32_BF16(kf1, qf1, zr);
      s4[i] = zr;
    }
    __builtin_amdgcn_s_setprio(0);

    // p = exp2(s*SCL - MC), masked by sign-extended bitfield
    const uint32_t w0 = mmc.x >> (g * 4);
    const uint32_t w1 = mmc.y >> (g * 4);
    #pragma unroll
    for(int i = 0; i < 4; ++i){
      const uint32_t ww = (i < 2) ? w0 : w1;
      #pragma unroll
      for(int j = 0; j < 4; ++j){
        const int bitpos = (i & 1) * 16 + j;
        float e = exp2f(fmaf(s4[i][j], SCL, -MC));
        uint32_t sm = (uint32_t)(((int)(ww << (31 - bitpos))) >> 31);
        s4[i][j] = __uint_as_float(sm & __float_as_uint(e));
      }
    }

    // pack P -> per-wave LDS (b64 writes)
    #pragma unroll
    for(int i = 0; i < 4; ++i){
      uint2 pk;
      pk.x = bfpack2(s4[i][0], s4[i][1]);
      pk.y = bfpack2(s4[i][2], s4[i][3]);
      *(uint2*)&PsmW[pW[i]] = pk;
    }

    // PV (+ denominator via ones-column MFMA)
    __builtin_amdgcn_s_setprio(1);
    #pragma unroll
    for(int c2 = 0; c2 < 2; ++c2){
      bf16x8 pf = *(const bf16x8*)&PsmW[pR[c2]];
      acl = MFMA_16x16x32_BF16(pf, ones, acl);
      #pragma unroll
      for(int tt = 0; tt < 4; ++tt){
        bf16x8 vf = *(const bf16x8*)&Vc[vOff[c2][tt]];
        acc[tt] = MFMA_16x16x32_BF16(pf, vf, acc[tt]);
      }
    }
    __builtin_amdgcn_s_setprio(0);

    // all my ds_reads of buf[cur] complete, then publish "done reading"
    asm volatile("s_waitcnt lgkmcnt(0)" ::: "memory");
    __builtin_amdgcn_s_barrier();
    cur ^= 1;
    mmc = mmn;
  }

  // finalize: l already in output-row layout (row = g*4+j)
  #pragma unroll
  for(int j = 0; j < 4; ++j){
    const float inv = 1.0f / acl[j];
    const int qr = qbase + g * 4 + j;
    #pragma unroll
    for(int tt = 0; tt < 4; ++tt)
      Xo[(size_t)(b * NS + qr) * ND + h * NDK + tt * 16 + l15] = f2bf(acc[tt][j] * inv);
  }
}

// ---------------- host launch ------------------------------------------------
extern "C" void kernel_launch(void* const* d_in, const int* in_sizes, int n_in,
                              void* d_out, int out_size, void* d_ws, size_t ws_size,
                              hipStream_t stream)
{
  const float* query = (const float*)d_in[0];
  const float* key   = (const float*)d_in[1];
  const float* value = (const float*)d_in[2];
  const int*   mask  = (const int*)d_in[3];
  const float* Wq = (const float*)d_in[4];
  const float* bq = (const float*)d_in[5];
  const float* Wk = (const float*)d_in[6];
  const float* bk = (const float*)d_in[7];
  const float* Wv = (const float*)d_in[8];
  const float* bv = (const float*)d_in[9];
  const float* Wo = (const float*)d_in[10];
  const float* bo = (const float*)d_in[11];
  float* out = (float*)d_out;

  const size_t NX = (size_t)NB * NS * ND;   // 4,194,304
  const size_t NW = (size_t)ND * ND;        // 1,048,576

  uint16_t* ws  = (uint16_t*)d_ws;
  uint16_t* Xq  = ws;            // bf16 activations
  uint16_t* Xk  = Xq  + NX;
  uint16_t* Xv  = Xk  + NX;
  uint16_t* Wqb = Xv  + NX;
  uint16_t* Wkb = Wqb + NW;
  uint16_t* Wvb = Wkb + NW;
  uint16_t* Wob = Wvb + NW;
  uint16_t* Qp  = Wob + NW;
  uint16_t* Kp  = Qp  + NX;
  uint16_t* Vt  = Kp  + NX;      // V^T written directly by proj epilogue (z==2)
  uint16_t* Xa  = Vt  + NX;
  unsigned long long* Mb = (unsigned long long*)(Xa + NX);   // 1MB, own slot

  const int nchunks = (int)((size_t)NB * NS * NS / 64);   // 131072

  prep_inputs<<<dim3(2048, 4), 256, 0, stream>>>(query, key, value, Xq, Xk, Xv,
                                                 mask, Mb, (int)(NX / 8), nchunks);
  cvt4_f32_bf16<<<dim3(512, 4), 256, 0, stream>>>(Wq, Wk, Wv, Wo, Wqb, Wkb, Wvb, Wob, (int)(NW / 8));

  dim3 gproj(ND / 128, (NB * NS) / 128, 3);
  gemm_bt<false><<<gproj, 256, 0, stream>>>(Xq, Xk, Xv,
                                            Wqb, Wkb, Wvb,
                                            bq, bk, bv,
                                            (void*)Qp, (void*)Kp, (void*)Vt,
                                            NB * NS, ND, ND, 2);

  attn_fwd<<<dim3(NS / 64, NH, NB), 256, 0, stream>>>(Qp, Kp, Vt, (const uint2*)Mb, Xa);

  dim3 gout(ND / 128, (NB * NS) / 128, 1);
  gemm_bt<true><<<gout, 256, 0, stream>>>(Xa, Xa, Xa,
                                          Wob, Wob, Wob,
                                          bo, bo, bo,
                                          (void*)out, (void*)out, (void*)out,
                                          NB * NS, ND, ND, -1);
}